// Round 1
// baseline (414.348 us; speedup 1.0000x reference)
//
#include <hip/hip_runtime.h>
#include <math.h>

#define PI_F 3.14159265358979323846f
#define NB 8
#define NH 128
#define NL 4096
#define LF 2049   // NL/2 + 1

__device__ __forceinline__ float gelu_exact(float x) {
  return 0.5f * x * (1.0f + erff(x * 0.70710678118654752f));
}

// ---------------- precompute: C~ = F^-1 C, B~ = Bbar F, T = D F ----------------
__global__ __launch_bounds__(128) void precomp1(
    const float* __restrict__ C2, const float* __restrict__ B2,
    const float* __restrict__ D,
    float* __restrict__ Bt, float* __restrict__ Ct, float* __restrict__ Tt) {
  int x = blockIdx.x, t = threadIdx.x, which = blockIdx.y;
  float sr = 0.f, si = 0.f;
  if (which == 0) {
    // B~[p=x][q=t] = sum_{q'} B2[x][q'] * e^{-2pi i q' t /128}; store Bt[q][p]
    for (int k = 0; k < 128; ++k) {
      float th = -(float)((k * t) & 127) * (2.f * PI_F / 128.f);
      float s, c; sincosf(th, &s, &c);
      float br = B2[(x * 128 + k) * 2], bi = B2[(x * 128 + k) * 2 + 1];
      sr += br * c - bi * s; si += br * s + bi * c;
    }
    Bt[(t * 128 + x) * 2] = sr; Bt[(t * 128 + x) * 2 + 1] = si;
  } else if (which == 1) {
    // C~[h=t][p=x] = (1/128) sum_{h'} e^{+2pi i t h'/128} C2[h'][x]; store Ct[p][h]
    for (int k = 0; k < 128; ++k) {
      float th = (float)((k * t) & 127) * (2.f * PI_F / 128.f);
      float s, c; sincosf(th, &s, &c);
      float cr = C2[(k * 128 + x) * 2], ci = C2[(k * 128 + x) * 2 + 1];
      sr += cr * c - ci * s; si += cr * s + ci * c;
    }
    Ct[(x * 128 + t) * 2] = sr * (1.f / 128.f);
    Ct[(x * 128 + t) * 2 + 1] = si * (1.f / 128.f);
  } else {
    // T[h'=x][q=t] = sum_{q'} D[x][q'] e^{-2pi i q' t/128}; store Tt[h'][q]
    for (int k = 0; k < 128; ++k) {
      float th = -(float)((k * t) & 127) * (2.f * PI_F / 128.f);
      float s, c; sincosf(th, &s, &c);
      float d = D[x * 128 + k];
      sr += d * c; si += d * s;
    }
    Tt[(x * 128 + t) * 2] = sr; Tt[(x * 128 + t) * 2 + 1] = si;
  }
}

// D~[h][q] = (1/128) sum_{h'} e^{+2pi i h h'/128} T[h'][q]; store Dt[q][h]
__global__ __launch_bounds__(128) void precomp2(const float* __restrict__ Tt,
                                                float* __restrict__ Dt) {
  int q = blockIdx.x, h = threadIdx.x;
  float sr = 0.f, si = 0.f;
  for (int k = 0; k < 128; ++k) {
    float th = (float)((k * h) & 127) * (2.f * PI_F / 128.f);
    float s, c; sincosf(th, &s, &c);
    float tr = Tt[(k * 128 + q) * 2], ti = Tt[(k * 128 + q) * 2 + 1];
    sr += tr * c - ti * s; si += tr * s + ti * c;
  }
  Dt[(q * 128 + h) * 2] = sr * (1.f / 128.f);
  Dt[(q * 128 + h) * 2 + 1] = si * (1.f / 128.f);
}

// ---------------- 2048-pt complex FFT in LDS (radix-2 DIT, bit-reversed input) ----------------
__device__ __forceinline__ void fft2048_lds(float* re, float* im,
                                            const float* twr, const float* twi,
                                            int tid) {
  for (int s = 1; s <= 11; ++s) {
    int half = 1 << (s - 1);
    int tsh = 11 - s;
    __syncthreads();
#pragma unroll
    for (int r = 0; r < 4; ++r) {
      int k = tid + (r << 8);
      int j = k & (half - 1);
      int base = ((k >> (s - 1)) << s) | j;
      int i2 = base + half;
      int ix = j << tsh;
      float wr = twr[ix], wi = twi[ix];
      float xr = re[i2], xi = im[i2];
      float tr = wr * xr - wi * xi;
      float ti = wr * xi + wi * xr;
      float ar = re[base], ai = im[base];
      re[i2] = ar - tr;   im[i2] = ai - ti;
      re[base] = ar + tr; im[base] = ai + ti;
    }
  }
  __syncthreads();
}

// ---------------- forward rfft-4096 per (b,h) row ----------------
__global__ __launch_bounds__(256) void fft_fwd(const float* __restrict__ u,
                                               float* __restrict__ Ur,
                                               float* __restrict__ Ui) {
  __shared__ float re[2048], im[2048], twr[1024], twi[1024];
  int tid = threadIdx.x;
  int row = blockIdx.x;
  const float2* src = (const float2*)(u + (size_t)row * NL);
#pragma unroll
  for (int r = 0; r < 4; ++r) {
    int j = tid + (r << 8);
    float th = -(float)j * (2.f * PI_F / 2048.f);
    float s, c; sincosf(th, &s, &c);
    twr[j] = c; twi[j] = s;
  }
#pragma unroll
  for (int r = 0; r < 8; ++r) {
    int n = tid + (r << 8);
    float2 v = src[n];
    int bj = __brev((unsigned)n) >> 21;
    re[bj] = v.x; im[bj] = v.y;
  }
  fft2048_lds(re, im, twr, twi, tid);
  size_t ob = (size_t)row * LF;
#pragma unroll
  for (int r = 0; r < 4; ++r) {
    int k = tid + (r << 8);
    if (k == 0) {
      float zr = re[0], zi = im[0];
      Ur[ob] = zr + zi;         Ui[ob] = 0.f;
      Ur[ob + 2048] = zr - zi;  Ui[ob + 2048] = 0.f;
      Ur[ob + 1024] = re[1024]; Ui[ob + 1024] = -im[1024];
    } else {
      float Ar = re[k], Ai = im[k];
      float Br = re[2048 - k], Bi = -im[2048 - k];     // conj(Z[M-k])
      float sr = 0.5f * (Ar + Br), si = 0.5f * (Ai + Bi);
      float dr = 0.5f * (Ar - Br), di = 0.5f * (Ai - Bi);
      float th = (float)k * (PI_F / 2048.f);
      float sn, cs; sincosf(th, &sn, &cs);
      float tr = cs * dr + sn * di;                    // W*d with W = (cs,-sn)
      float ti = cs * di - sn * dr;
      Ur[ob + k] = sr + ti;                            // s + (-i)(W*d)
      Ui[ob + k] = si - tr;
      // U[M-k]: A' = Z[M-k], B' = conj(Z[k]), W' = (-cs,-sn)
      float A2r = re[2048 - k], A2i = im[2048 - k];
      float B2r = Ar, B2i = -Ai;
      float s2r = 0.5f * (A2r + B2r), s2i = 0.5f * (A2i + B2i);
      float d2r = 0.5f * (A2r - B2r), d2i = 0.5f * (A2i - B2i);
      float t2r = -cs * d2r + sn * d2i;
      float t2i = -cs * d2i - sn * d2r;
      Ur[ob + 2048 - k] = s2r + t2i;
      Ui[ob + 2048 - k] = s2i - t2r;
    }
  }
}

// ---------------- mixing: Y = C~ diag(kernel) B~ U + D~ U, per (b, l-tile) ----------------
__global__ __launch_bounds__(256) void mix_kernel(
    const float* __restrict__ Ur, const float* __restrict__ Ui,
    const float* __restrict__ Bt, const float* __restrict__ Ct,
    const float* __restrict__ Dt, const float* __restrict__ Lam,
    float* __restrict__ Yr, float* __restrict__ Yi) {
  __shared__ float sUr[128][32], sUi[128][32], sVr[128][32], sVi[128][32];
  int tid = threadIdx.x;
  int b = blockIdx.y;
  size_t ub = (size_t)b * NH * LF;

  if (blockIdx.x == 64) {  // cheap path: the single Nyquist column l = 2048
    int t = tid;
    if (t < 128) {
      sUr[t][0] = Ur[ub + (size_t)t * LF + 2048];
      sUi[t][0] = Ui[ub + (size_t)t * LF + 2048];
    }
    __syncthreads();
    if (t < 128) {
      float ar = 0.f, ai = 0.f;
      for (int q = 0; q < 128; ++q) {
        float ur = sUr[q][0], ui = sUi[q][0];
        float br = Bt[(q * 128 + t) * 2], bi = Bt[(q * 128 + t) * 2 + 1];
        ar += br * ur - bi * ui; ai += br * ui + bi * ur;
      }
      float a = Lam[2 * t], bb = Lam[2 * t + 1];
      float dx = -a, dy = PI_F - bb;  // omega = pi at l = 2048
      float inv = 1.f / (dx * dx + dy * dy);
      float kr = dx * inv, ki = -dy * inv;
      sVr[t][0] = kr * ar - ki * ai;
      sVi[t][0] = kr * ai + ki * ar;
    }
    __syncthreads();
    if (t < 128) {
      float ar = 0.f, ai = 0.f;
      for (int q = 0; q < 128; ++q) {
        float ur = sUr[q][0], ui = sUi[q][0];
        float vr = sVr[q][0], vi = sVi[q][0];
        float cr = Ct[(q * 128 + t) * 2], ci = Ct[(q * 128 + t) * 2 + 1];
        float dr = Dt[(q * 128 + t) * 2], di = Dt[(q * 128 + t) * 2 + 1];
        ar += cr * vr - ci * vi + dr * ur - di * ui;
        ai += cr * vi + ci * vr + dr * ui + di * ur;
      }
      Yr[ub + (size_t)t * LF + 2048] = ar;
      Yi[ub + (size_t)t * LF + 2048] = ai;
    }
    return;
  }

  int lane = tid & 31, g = tid >> 5;
  int l = blockIdx.x * 32 + lane;  // l <= 2047 here, always valid
#pragma unroll
  for (int rep = 0; rep < 16; ++rep) {
    int q = rep * 8 + g;
    sUr[q][lane] = Ur[ub + (size_t)q * LF + l];
    sUi[q][lane] = Ui[ub + (size_t)q * LF + l];
  }
  __syncthreads();
  float omega = (float)l * (PI_F / 2048.f);

  for (int pass = 0; pass < 4; ++pass) {
    int p0 = pass * 32 + g * 4;
    float accr[4] = {0, 0, 0, 0}, acci[4] = {0, 0, 0, 0};
#pragma unroll 4
    for (int q = 0; q < 128; ++q) {
      float ur = sUr[q][lane], ui = sUi[q][lane];
      const float4* bp = (const float4*)(Bt + (size_t)(q * 128 + p0) * 2);
      float4 m0 = bp[0], m1 = bp[1];
      accr[0] += m0.x * ur - m0.y * ui; acci[0] += m0.x * ui + m0.y * ur;
      accr[1] += m0.z * ur - m0.w * ui; acci[1] += m0.z * ui + m0.w * ur;
      accr[2] += m1.x * ur - m1.y * ui; acci[2] += m1.x * ui + m1.y * ur;
      accr[3] += m1.z * ur - m1.w * ui; acci[3] += m1.z * ui + m1.w * ur;
    }
#pragma unroll
    for (int k = 0; k < 4; ++k) {
      int p = p0 + k;
      float a = Lam[2 * p], bb = Lam[2 * p + 1];
      float dx = -a, dy = omega - bb;
      float inv = 1.f / (dx * dx + dy * dy);
      float kr = dx * inv, ki = -dy * inv;  // 1/(i*omega - lambda)
      sVr[p][lane] = kr * accr[k] - ki * acci[k];
      sVi[p][lane] = kr * acci[k] + ki * accr[k];
    }
  }
  __syncthreads();

  for (int pass = 0; pass < 4; ++pass) {
    int h0 = pass * 32 + g * 4;
    float accr[4] = {0, 0, 0, 0}, acci[4] = {0, 0, 0, 0};
#pragma unroll 2
    for (int q = 0; q < 128; ++q) {
      float ur = sUr[q][lane], ui = sUi[q][lane];
      float vr = sVr[q][lane], vi = sVi[q][lane];
      const float4* cp = (const float4*)(Ct + (size_t)(q * 128 + h0) * 2);
      const float4* dp = (const float4*)(Dt + (size_t)(q * 128 + h0) * 2);
      float4 c0 = cp[0], c1 = cp[1];
      float4 d0 = dp[0], d1 = dp[1];
      accr[0] += c0.x * vr - c0.y * vi + d0.x * ur - d0.y * ui;
      acci[0] += c0.x * vi + c0.y * vr + d0.x * ui + d0.y * ur;
      accr[1] += c0.z * vr - c0.w * vi + d0.z * ur - d0.w * ui;
      acci[1] += c0.z * vi + c0.w * vr + d0.z * ui + d0.w * ur;
      accr[2] += c1.x * vr - c1.y * vi + d1.x * ur - d1.y * ui;
      acci[2] += c1.x * vi + c1.y * vr + d1.x * ui + d1.y * ur;
      accr[3] += c1.z * vr - c1.w * vi + d1.z * ur - d1.w * ui;
      acci[3] += c1.z * vi + c1.w * vr + d1.z * ui + d1.w * ur;
    }
#pragma unroll
    for (int k = 0; k < 4; ++k) {
      int h = h0 + k;
      Yr[ub + (size_t)h * LF + l] = accr[k];
      Yi[ub + (size_t)h * LF + l] = acci[k];
    }
  }
}

// ---------------- inverse rfft-4096 per (b,h) row, fused exact GELU ----------------
__global__ __launch_bounds__(256) void fft_inv_gelu(const float* __restrict__ Yr,
                                                    const float* __restrict__ Yi,
                                                    float* __restrict__ out) {
  __shared__ float re[2048], im[2048], twr[1024], twi[1024];
  int tid = threadIdx.x;
  int row = blockIdx.x;
  size_t ob = (size_t)row * LF;
#pragma unroll
  for (int r = 0; r < 4; ++r) {
    int j = tid + (r << 8);
    float th = (float)j * (2.f * PI_F / 2048.f);  // +i twiddles for inverse
    float s, c; sincosf(th, &s, &c);
    twr[j] = c; twi[j] = s;
  }
#pragma unroll
  for (int r = 0; r < 4; ++r) {
    int k = tid + (r << 8);
    if (k == 0) {
      float y0 = Yr[ob];          // Im(Y[0]) discarded (pocketfft semantics)
      float yN = Yr[ob + 2048];   // Im(Y[N/2]) discarded
      re[0] = 0.5f * (y0 + yN);
      im[0] = 0.5f * (y0 - yN);
      int bj = __brev(1024u) >> 21;
      re[bj] = Yr[ob + 1024];
      im[bj] = -Yi[ob + 1024];    // Z[1024] = conj(Y[1024])
    } else {
      float Ar = Yr[ob + k], Ai = Yi[ob + k];
      float Mr = Yr[ob + 2048 - k], Mi = Yi[ob + 2048 - k];
      float Br = Mr, Bi = -Mi;    // conj(Y[M-k])
      float sr = 0.5f * (Ar + Br), si = 0.5f * (Ai + Bi);
      float dr = 0.5f * (Ar - Br), di = 0.5f * (Ai - Bi);
      float th = (float)k * (PI_F / 2048.f);
      float sn, cs; sincosf(th, &sn, &cs);
      float e1 = cs * di + sn * dr;
      float e2 = cs * dr - sn * di;
      int bk = __brev((unsigned)k) >> 21;
      int bm = __brev((unsigned)(2048 - k)) >> 21;
      re[bk] = sr - e1; im[bk] = si + e2;
      re[bm] = sr + e1; im[bm] = -si + e2;
    }
  }
  fft2048_lds(re, im, twr, twi, tid);
  float2* dst = (float2*)(out + (size_t)row * NL);
  const float sc = 1.f / 2048.f;
#pragma unroll
  for (int r = 0; r < 8; ++r) {
    int n = tid + (r << 8);
    float x = re[n] * sc, y = im[n] * sc;
    dst[n] = make_float2(gelu_exact(x), gelu_exact(y));
  }
}

extern "C" void kernel_launch(void* const* d_in, const int* in_sizes, int n_in,
                              void* d_out, int out_size, void* d_ws, size_t ws_size,
                              hipStream_t stream) {
  const float* u   = (const float*)d_in[0];
  const float* C2  = (const float*)d_in[1];
  const float* B2  = (const float*)d_in[2];
  const float* D   = (const float*)d_in[3];
  const float* Lam = (const float*)d_in[4];
  float* out = (float*)d_out;
  float* ws = (float*)d_ws;

  const size_t nU = (size_t)NB * NH * LF;  // 2,098,176 floats per plane
  float *Ur, *Ui, *Yr, *Yi, *Bt;
  size_t need_full = (4 * nU + 4 * 32768) * sizeof(float);  // ~34.1 MB
  if (ws_size >= need_full) {
    Ur = ws; Ui = ws + nU; Yr = ws + 2 * nU; Yi = ws + 3 * nU;
    Bt = ws + 4 * nU;
  } else {
    // Alias Y onto U: safe — each (b,l) column is read fully into LDS by its
    // owning mix block before that block writes Y to the same column.
    Ur = ws; Ui = ws + nU; Yr = Ur; Yi = Ui;
    Bt = ws + 2 * nU;
  }
  float* Ct = Bt + 32768;
  float* Dt = Ct + 32768;
  float* Tt = Dt + 32768;

  precomp1<<<dim3(128, 3), 128, 0, stream>>>(C2, B2, D, Bt, Ct, Tt);
  precomp2<<<128, 128, 0, stream>>>(Tt, Dt);
  fft_fwd<<<NB * NH, 256, 0, stream>>>(u, Ur, Ui);
  mix_kernel<<<dim3(65, NB), 256, 0, stream>>>(Ur, Ui, Bt, Ct, Dt, Lam, Yr, Yi);
  fft_inv_gelu<<<NB * NH, 256, 0, stream>>>(Yr, Yi, out);
}

// Round 2
// 398.043 us; speedup vs baseline: 1.0410x; 1.0410x over previous
//
#include <hip/hip_runtime.h>
#include <math.h>

#define PI_F 3.14159265358979323846f
#define NB 8
#define NH 128
#define NL 4096
#define LF 2049   // NL/2 + 1

__device__ __forceinline__ float gelu_exact(float x) {
  return 0.5f * x * (1.0f + erff(x * 0.70710678118654752f));
}

// ---------------- precompute: C~ = F^-1 C, B~ = Bbar F, T = D F ----------------
__global__ __launch_bounds__(128) void precomp1(
    const float* __restrict__ C2, const float* __restrict__ B2,
    const float* __restrict__ D,
    float* __restrict__ Bt, float* __restrict__ Ct, float* __restrict__ Tt) {
  int x = blockIdx.x, t = threadIdx.x, which = blockIdx.y;
  float sr = 0.f, si = 0.f;
  if (which == 0) {
    // B~[p=x][q=t]; store Bt[q][p] (q-major rows, p contiguous)
    for (int k = 0; k < 128; ++k) {
      float th = -(float)((k * t) & 127) * (2.f * PI_F / 128.f);
      float s, c; sincosf(th, &s, &c);
      float br = B2[(x * 128 + k) * 2], bi = B2[(x * 128 + k) * 2 + 1];
      sr += br * c - bi * s; si += br * s + bi * c;
    }
    Bt[(t * 128 + x) * 2] = sr; Bt[(t * 128 + x) * 2 + 1] = si;
  } else if (which == 1) {
    // C~[h=t][p=x]; store Ct[p][h] (p-major rows, h contiguous)
    for (int k = 0; k < 128; ++k) {
      float th = (float)((k * t) & 127) * (2.f * PI_F / 128.f);
      float s, c; sincosf(th, &s, &c);
      float cr = C2[(k * 128 + x) * 2], ci = C2[(k * 128 + x) * 2 + 1];
      sr += cr * c - ci * s; si += cr * s + ci * c;
    }
    Ct[(x * 128 + t) * 2] = sr * (1.f / 128.f);
    Ct[(x * 128 + t) * 2 + 1] = si * (1.f / 128.f);
  } else {
    // T[h'=x][q=t] = sum_{q'} D[x][q'] e^{-2pi i q' t/128}; store Tt[h'][q]
    for (int k = 0; k < 128; ++k) {
      float th = -(float)((k * t) & 127) * (2.f * PI_F / 128.f);
      float s, c; sincosf(th, &s, &c);
      float d = D[x * 128 + k];
      sr += d * c; si += d * s;
    }
    Tt[(x * 128 + t) * 2] = sr; Tt[(x * 128 + t) * 2 + 1] = si;
  }
}

// D~[h][q] = (1/128) sum_{h'} e^{+2pi i h h'/128} T[h'][q]; store Dt[q][h]
__global__ __launch_bounds__(128) void precomp2(const float* __restrict__ Tt,
                                                float* __restrict__ Dt) {
  int q = blockIdx.x, h = threadIdx.x;
  float sr = 0.f, si = 0.f;
  for (int k = 0; k < 128; ++k) {
    float th = (float)((k * h) & 127) * (2.f * PI_F / 128.f);
    float s, c; sincosf(th, &s, &c);
    float tr = Tt[(k * 128 + q) * 2], ti = Tt[(k * 128 + q) * 2 + 1];
    sr += tr * c - ti * s; si += tr * s + ti * c;
  }
  Dt[(q * 128 + h) * 2] = sr * (1.f / 128.f);
  Dt[(q * 128 + h) * 2 + 1] = si * (1.f / 128.f);
}

// ---------------- 2048-pt complex FFT in LDS, radix-4 fused DIT ----------------
// In-place, bit-reversed input order (identical layout to the radix-2 cascade;
// stage pairs (1,2)(3,4)(5,6)(7,8)(9,10) fused, stage 11 radix-2).
template <bool FWD>
__device__ __forceinline__ void fft2048_r4(float* __restrict__ re, float* __restrict__ im,
                                           const float* __restrict__ twr,
                                           const float* __restrict__ twi, int tid) {
  // stage (1,2): j==0, all twiddles 1; contiguous quad -> float4 LDS ops
  __syncthreads();
  {
    float4* re4 = (float4*)re;
    float4* im4 = (float4*)im;
#pragma unroll
    for (int r = 0; r < 2; ++r) {
      int k = tid + (r << 8);
      float4 xr = re4[k], xi = im4[k];
      float a0r = xr.x + xr.y, a0i = xi.x + xi.y;
      float a1r = xr.x - xr.y, a1i = xi.x - xi.y;
      float a2r = xr.z + xr.w, a2i = xi.z + xi.w;
      float a3r = xr.z - xr.w, a3i = xi.z - xi.w;
      float mr = FWD ? a3i : -a3i;
      float mi = FWD ? -a3r : a3r;
      re4[k] = make_float4(a0r + a2r, a1r + mr, a0r - a2r, a1r - mr);
      im4[k] = make_float4(a0i + a2i, a1i + mi, a0i - a2i, a1i - mi);
    }
  }
#pragma unroll
  for (int s = 3; s <= 9; s += 2) {
    int half = 1 << (s - 1);
    __syncthreads();
#pragma unroll
    for (int r = 0; r < 2; ++r) {
      int k = tid + (r << 8);
      int j = k & (half - 1);
      int base = ((k >> (s - 1)) << (s + 1)) | j;
      int i0 = base, i1 = base + half, i2 = base + 2 * half, i3 = base + 3 * half;
      float w1r = twr[j << (11 - s)], w1i = twi[j << (11 - s)];
      float w2r = twr[j << (10 - s)], w2i = twi[j << (10 - s)];
      float x0r = re[i0], x0i = im[i0];
      float x1r = re[i1], x1i = im[i1];
      float x2r = re[i2], x2i = im[i2];
      float x3r = re[i3], x3i = im[i3];
      float t1r = fmaf(w1r, x1r, -w1i * x1i), t1i = fmaf(w1r, x1i, w1i * x1r);
      float t3r = fmaf(w1r, x3r, -w1i * x3i), t3i = fmaf(w1r, x3i, w1i * x3r);
      float a0r = x0r + t1r, a0i = x0i + t1i;
      float a1r = x0r - t1r, a1i = x0i - t1i;
      float a2r = x2r + t3r, a2i = x2i + t3i;
      float a3r = x2r - t3r, a3i = x2i - t3i;
      float u2r = fmaf(w2r, a2r, -w2i * a2i), u2i = fmaf(w2r, a2i, w2i * a2r);
      float u3r = fmaf(w2r, a3r, -w2i * a3i), u3i = fmaf(w2r, a3i, w2i * a3r);
      re[i0] = a0r + u2r; im[i0] = a0i + u2i;
      re[i2] = a0r - u2r; im[i2] = a0i - u2i;
      float mr = FWD ? u3i : -u3i;
      float mi = FWD ? -u3r : u3r;
      re[i1] = a1r + mr; im[i1] = a1i + mi;
      re[i3] = a1r - mr; im[i3] = a1i - mi;
    }
  }
  // stage 11 radix-2
  __syncthreads();
#pragma unroll
  for (int r = 0; r < 4; ++r) {
    int k = tid + (r << 8);
    float wr = twr[k], wi = twi[k];
    float xr = re[k + 1024], xi = im[k + 1024];
    float tr = fmaf(wr, xr, -wi * xi), ti = fmaf(wr, xi, wi * xr);
    float ar = re[k], ai = im[k];
    re[k + 1024] = ar - tr; im[k + 1024] = ai - ti;
    re[k] = ar + tr;        im[k] = ai + ti;
  }
  __syncthreads();
}

// ---------------- forward rfft-4096 per (b,h) row ----------------
__global__ __launch_bounds__(256) void fft_fwd(const float* __restrict__ u,
                                               float* __restrict__ Ur,
                                               float* __restrict__ Ui) {
  __shared__ __align__(16) float re[2048], im[2048];
  __shared__ float twr[1024], twi[1024];
  int tid = threadIdx.x;
  int row = blockIdx.x;
  const float2* src = (const float2*)(u + (size_t)row * NL);
#pragma unroll
  for (int r = 0; r < 4; ++r) {
    int j = tid + (r << 8);
    float th = -(float)j * (2.f * PI_F / 2048.f);
    float s, c; sincosf(th, &s, &c);
    twr[j] = c; twi[j] = s;
  }
#pragma unroll
  for (int r = 0; r < 8; ++r) {
    int n = tid + (r << 8);
    float2 v = src[n];
    int bj = __brev((unsigned)n) >> 21;
    re[bj] = v.x; im[bj] = v.y;
  }
  fft2048_r4<true>(re, im, twr, twi, tid);
  size_t ob = (size_t)row * LF;
#pragma unroll
  for (int r = 0; r < 4; ++r) {
    int k = tid + (r << 8);
    if (k == 0) {
      float zr = re[0], zi = im[0];
      Ur[ob] = zr + zi;         Ui[ob] = 0.f;
      Ur[ob + 2048] = zr - zi;  Ui[ob + 2048] = 0.f;
      Ur[ob + 1024] = re[1024]; Ui[ob + 1024] = -im[1024];
    } else {
      float Ar = re[k], Ai = im[k];
      float Br = re[2048 - k], Bi = -im[2048 - k];     // conj(Z[M-k])
      float sr = 0.5f * (Ar + Br), si = 0.5f * (Ai + Bi);
      float dr = 0.5f * (Ar - Br), di = 0.5f * (Ai - Bi);
      float th = (float)k * (PI_F / 2048.f);
      float sn, cs; sincosf(th, &sn, &cs);
      float tr = cs * dr + sn * di;                    // W*d with W = (cs,-sn)
      float ti = cs * di - sn * dr;
      Ur[ob + k] = sr + ti;
      Ui[ob + k] = si - tr;
      float A2r = re[2048 - k], A2i = im[2048 - k];
      float B2r = Ar, B2i = -Ai;
      float s2r = 0.5f * (A2r + B2r), s2i = 0.5f * (A2i + B2i);
      float d2r = 0.5f * (A2r - B2r), d2i = 0.5f * (A2i - B2i);
      float t2r = -cs * d2r + sn * d2i;
      float t2i = -cs * d2i - sn * d2r;
      Ur[ob + 2048 - k] = s2r + t2i;
      Ui[ob + 2048 - k] = s2i - t2r;
    }
  }
}

// ---------------- mixing: Y = C~ diag(kernel) B~ U + D~ U, per (b, l-tile) ----------------
// 256 threads = 8 half-wave groups of 32 lanes; lane = column, group owns a
// 16-wide p (pass1) / h (pass2) panel -> 32 fp32 accumulators per thread.
__global__ __launch_bounds__(256) void mix_kernel(
    const float* __restrict__ Ur, const float* __restrict__ Ui,
    const float* __restrict__ Bt, const float* __restrict__ Ct,
    const float* __restrict__ Dt, const float* __restrict__ Lam,
    float* __restrict__ Yr, float* __restrict__ Yi) {
  __shared__ float sUr[128][32], sUi[128][32], sVr[128][32], sVi[128][32];
  int tid = threadIdx.x;
  int b = blockIdx.y;
  size_t ub = (size_t)b * NH * LF;

  if (blockIdx.x == 64) {  // cheap path: the single Nyquist column l = 2048
    int t = tid;
    if (t < 128) {
      sUr[t][0] = Ur[ub + (size_t)t * LF + 2048];
      sUi[t][0] = Ui[ub + (size_t)t * LF + 2048];
    }
    __syncthreads();
    if (t < 128) {
      float ar = 0.f, ai = 0.f;
      for (int q = 0; q < 128; ++q) {
        float ur = sUr[q][0], ui = sUi[q][0];
        float br = Bt[(q * 128 + t) * 2], bi = Bt[(q * 128 + t) * 2 + 1];
        ar = fmaf(br, ur, fmaf(-bi, ui, ar));
        ai = fmaf(br, ui, fmaf(bi, ur, ai));
      }
      float a = Lam[2 * t], bb = Lam[2 * t + 1];
      float dx = -a, dy = PI_F - bb;  // omega = pi at l = 2048
      float inv = 1.f / (dx * dx + dy * dy);
      float kr = dx * inv, ki = -dy * inv;
      sVr[t][0] = kr * ar - ki * ai;
      sVi[t][0] = kr * ai + ki * ar;
    }
    __syncthreads();
    if (t < 128) {
      float ar = 0.f, ai = 0.f;
      for (int q = 0; q < 128; ++q) {
        float ur = sUr[q][0], ui = sUi[q][0];
        float vr = sVr[q][0], vi = sVi[q][0];
        float cr = Ct[(q * 128 + t) * 2], ci = Ct[(q * 128 + t) * 2 + 1];
        float dr = Dt[(q * 128 + t) * 2], di = Dt[(q * 128 + t) * 2 + 1];
        ar += cr * vr - ci * vi + dr * ur - di * ui;
        ai += cr * vi + ci * vr + dr * ui + di * ur;
      }
      Yr[ub + (size_t)t * LF + 2048] = ar;
      Yi[ub + (size_t)t * LF + 2048] = ai;
    }
    return;
  }

  int lane = tid & 31, g = tid >> 5;      // g in [0,8)
  int l = blockIdx.x * 32 + lane;         // l <= 2047 here, always valid
#pragma unroll
  for (int rep = 0; rep < 16; ++rep) {
    int q = rep * 8 + g;
    sUr[q][lane] = Ur[ub + (size_t)q * LF + l];
    sUi[q][lane] = Ui[ub + (size_t)q * LF + l];
  }
  __syncthreads();
  float omega = (float)l * (PI_F / 2048.f);

  float ar[16], ai[16];
  // ---- pass 1: V = B~ U, panel p0..p0+15 ----
  {
    int p0 = g * 16;
#pragma unroll
    for (int k = 0; k < 16; ++k) { ar[k] = 0.f; ai[k] = 0.f; }
#pragma unroll 2
    for (int q = 0; q < 128; ++q) {
      float ur = sUr[q][lane], ui = sUi[q][lane];
      const float4* bp = (const float4*)(Bt + ((size_t)q * 128 + p0) * 2);
#pragma unroll
      for (int kk = 0; kk < 8; ++kk) {
        float4 m = bp[kk];
        ar[2 * kk]     = fmaf(m.x, ur, fmaf(-m.y, ui, ar[2 * kk]));
        ai[2 * kk]     = fmaf(m.x, ui, fmaf( m.y, ur, ai[2 * kk]));
        ar[2 * kk + 1] = fmaf(m.z, ur, fmaf(-m.w, ui, ar[2 * kk + 1]));
        ai[2 * kk + 1] = fmaf(m.z, ui, fmaf( m.w, ur, ai[2 * kk + 1]));
      }
    }
#pragma unroll
    for (int k = 0; k < 16; ++k) {
      int p = p0 + k;
      float a = Lam[2 * p], bb = Lam[2 * p + 1];
      float dx = -a, dy = omega - bb;
      float inv = 1.f / (dx * dx + dy * dy);
      float kr = dx * inv, ki = -dy * inv;  // 1/(i*omega - lambda)
      sVr[p][lane] = kr * ar[k] - ki * ai[k];
      sVi[p][lane] = kr * ai[k] + ki * ar[k];
    }
  }
  __syncthreads();

  // ---- pass 2: Y = C~ V' + D~ U, panel h0..h0+15 ----
  {
    int h0 = g * 16;
#pragma unroll
    for (int k = 0; k < 16; ++k) { ar[k] = 0.f; ai[k] = 0.f; }
#pragma unroll 2
    for (int q = 0; q < 128; ++q) {
      float ur = sUr[q][lane], ui = sUi[q][lane];
      float vr = sVr[q][lane], vi = sVi[q][lane];
      const float4* cp = (const float4*)(Ct + ((size_t)q * 128 + h0) * 2);
      const float4* dp = (const float4*)(Dt + ((size_t)q * 128 + h0) * 2);
#pragma unroll
      for (int kk = 0; kk < 8; ++kk) {
        float4 c = cp[kk];
        float4 d = dp[kk];
        int k0 = 2 * kk, k1 = 2 * kk + 1;
        ar[k0] = fmaf(c.x, vr, fmaf(-c.y, vi, fmaf(d.x, ur, fmaf(-d.y, ui, ar[k0]))));
        ai[k0] = fmaf(c.x, vi, fmaf( c.y, vr, fmaf(d.x, ui, fmaf( d.y, ur, ai[k0]))));
        ar[k1] = fmaf(c.z, vr, fmaf(-c.w, vi, fmaf(d.z, ur, fmaf(-d.w, ui, ar[k1]))));
        ai[k1] = fmaf(c.z, vi, fmaf( c.w, vr, fmaf(d.z, ui, fmaf( d.w, ur, ai[k1]))));
      }
    }
#pragma unroll
    for (int k = 0; k < 16; ++k) {
      int h = h0 + k;
      Yr[ub + (size_t)h * LF + l] = ar[k];
      Yi[ub + (size_t)h * LF + l] = ai[k];
    }
  }
}

// ---------------- inverse rfft-4096 per (b,h) row, fused exact GELU ----------------
__global__ __launch_bounds__(256) void fft_inv_gelu(const float* __restrict__ Yr,
                                                    const float* __restrict__ Yi,
                                                    float* __restrict__ out) {
  __shared__ __align__(16) float re[2048], im[2048];
  __shared__ float twr[1024], twi[1024];
  int tid = threadIdx.x;
  int row = blockIdx.x;
  size_t ob = (size_t)row * LF;
#pragma unroll
  for (int r = 0; r < 4; ++r) {
    int j = tid + (r << 8);
    float th = (float)j * (2.f * PI_F / 2048.f);  // +i twiddles for inverse
    float s, c; sincosf(th, &s, &c);
    twr[j] = c; twi[j] = s;
  }
#pragma unroll
  for (int r = 0; r < 4; ++r) {
    int k = tid + (r << 8);
    if (k == 0) {
      float y0 = Yr[ob];          // Im(Y[0]) discarded (pocketfft semantics)
      float yN = Yr[ob + 2048];   // Im(Y[N/2]) discarded
      re[0] = 0.5f * (y0 + yN);
      im[0] = 0.5f * (y0 - yN);
      int bj = __brev(1024u) >> 21;
      re[bj] = Yr[ob + 1024];
      im[bj] = -Yi[ob + 1024];    // Z[1024] = conj(Y[1024])
    } else {
      float Ar = Yr[ob + k], Ai = Yi[ob + k];
      float Mr = Yr[ob + 2048 - k], Mi = Yi[ob + 2048 - k];
      float Br = Mr, Bi = -Mi;    // conj(Y[M-k])
      float sr = 0.5f * (Ar + Br), si = 0.5f * (Ai + Bi);
      float dr = 0.5f * (Ar - Br), di = 0.5f * (Ai - Bi);
      float th = (float)k * (PI_F / 2048.f);
      float sn, cs; sincosf(th, &sn, &cs);
      float e1 = cs * di + sn * dr;
      float e2 = cs * dr - sn * di;
      int bk = __brev((unsigned)k) >> 21;
      int bm = __brev((unsigned)(2048 - k)) >> 21;
      re[bk] = sr - e1; im[bk] = si + e2;
      re[bm] = sr + e1; im[bm] = -si + e2;
    }
  }
  fft2048_r4<false>(re, im, twr, twi, tid);
  float2* dst = (float2*)(out + (size_t)row * NL);
  const float sc = 1.f / 2048.f;
#pragma unroll
  for (int r = 0; r < 8; ++r) {
    int n = tid + (r << 8);
    float x = re[n] * sc, y = im[n] * sc;
    dst[n] = make_float2(gelu_exact(x), gelu_exact(y));
  }
}

extern "C" void kernel_launch(void* const* d_in, const int* in_sizes, int n_in,
                              void* d_out, int out_size, void* d_ws, size_t ws_size,
                              hipStream_t stream) {
  const float* u   = (const float*)d_in[0];
  const float* C2  = (const float*)d_in[1];
  const float* B2  = (const float*)d_in[2];
  const float* D   = (const float*)d_in[3];
  const float* Lam = (const float*)d_in[4];
  float* out = (float*)d_out;
  float* ws = (float*)d_ws;

  const size_t nU = (size_t)NB * NH * LF;  // 2,098,176 floats per plane
  float *Ur, *Ui, *Yr, *Yi, *Bt;
  size_t need_full = (4 * nU + 4 * 32768) * sizeof(float);  // ~34.1 MB
  if (ws_size >= need_full) {
    Ur = ws; Ui = ws + nU; Yr = ws + 2 * nU; Yi = ws + 3 * nU;
    Bt = ws + 4 * nU;
  } else {
    // Alias Y onto U: safe — each (b,l) column is read fully into LDS by its
    // owning mix block before that block writes Y to the same column.
    Ur = ws; Ui = ws + nU; Yr = Ur; Yi = Ui;
    Bt = ws + 2 * nU;
  }
  float* Ct = Bt + 32768;
  float* Dt = Ct + 32768;
  float* Tt = Dt + 32768;

  precomp1<<<dim3(128, 3), 128, 0, stream>>>(C2, B2, D, Bt, Ct, Tt);
  precomp2<<<128, 128, 0, stream>>>(Tt, Dt);
  fft_fwd<<<NB * NH, 256, 0, stream>>>(u, Ur, Ui);
  mix_kernel<<<dim3(65, NB), 256, 0, stream>>>(Ur, Ui, Bt, Ct, Dt, Lam, Yr, Yi);
  fft_inv_gelu<<<NB * NH, 256, 0, stream>>>(Yr, Yi, out);
}

// Round 3
// 363.658 us; speedup vs baseline: 1.1394x; 1.0946x over previous
//
#include <hip/hip_runtime.h>
#include <math.h>

#define PI_F 3.14159265358979323846f
#define NB 8
#define NH 128
#define NL 4096
#define LF 2049   // NL/2 + 1

typedef float2 cpx;

__device__ __forceinline__ float gelu_exact(float x) {
  return 0.5f * x * (1.0f + erff(x * 0.70710678118654752f));
}
__device__ __forceinline__ cpx cadd(cpx a, cpx b) { return make_float2(a.x + b.x, a.y + b.y); }
__device__ __forceinline__ cpx csub(cpx a, cpx b) { return make_float2(a.x - b.x, a.y - b.y); }
__device__ __forceinline__ cpx cmul(cpx a, cpx b) {
  return make_float2(fmaf(a.x, b.x, -a.y * b.y), fmaf(a.x, b.y, a.y * b.x));
}
template <int SGN>
__device__ __forceinline__ cpx mulJ(cpx a) {  // multiply by SGN*i
  return (SGN < 0) ? make_float2(a.y, -a.x) : make_float2(-a.y, a.x);
}

// ---------------- precompute: C~ = F^-1 C, B~ = Bbar F, T = D F ----------------
__global__ __launch_bounds__(128) void precomp1(
    const float* __restrict__ C2, const float* __restrict__ B2,
    const float* __restrict__ D,
    float* __restrict__ Bt, float* __restrict__ Ct, float* __restrict__ Tt) {
  int x = blockIdx.x, t = threadIdx.x, which = blockIdx.y;
  float sr = 0.f, si = 0.f;
  if (which == 0) {
    for (int k = 0; k < 128; ++k) {
      float th = -(float)((k * t) & 127) * (2.f * PI_F / 128.f);
      float s, c; sincosf(th, &s, &c);
      float br = B2[(x * 128 + k) * 2], bi = B2[(x * 128 + k) * 2 + 1];
      sr += br * c - bi * s; si += br * s + bi * c;
    }
    Bt[(t * 128 + x) * 2] = sr; Bt[(t * 128 + x) * 2 + 1] = si;
  } else if (which == 1) {
    for (int k = 0; k < 128; ++k) {
      float th = (float)((k * t) & 127) * (2.f * PI_F / 128.f);
      float s, c; sincosf(th, &s, &c);
      float cr = C2[(k * 128 + x) * 2], ci = C2[(k * 128 + x) * 2 + 1];
      sr += cr * c - ci * s; si += cr * s + ci * c;
    }
    Ct[(x * 128 + t) * 2] = sr * (1.f / 128.f);
    Ct[(x * 128 + t) * 2 + 1] = si * (1.f / 128.f);
  } else {
    for (int k = 0; k < 128; ++k) {
      float th = -(float)((k * t) & 127) * (2.f * PI_F / 128.f);
      float s, c; sincosf(th, &s, &c);
      float d = D[x * 128 + k];
      sr += d * c; si += d * s;
    }
    Tt[(x * 128 + t) * 2] = sr; Tt[(x * 128 + t) * 2 + 1] = si;
  }
}

__global__ __launch_bounds__(128) void precomp2(const float* __restrict__ Tt,
                                                float* __restrict__ Dt) {
  int q = blockIdx.x, h = threadIdx.x;
  float sr = 0.f, si = 0.f;
  for (int k = 0; k < 128; ++k) {
    float th = (float)((k * h) & 127) * (2.f * PI_F / 128.f);
    float s, c; sincosf(th, &s, &c);
    float tr = Tt[(k * 128 + q) * 2], ti = Tt[(k * 128 + q) * 2 + 1];
    sr += tr * c - ti * s; si += tr * s + ti * c;
  }
  Dt[(q * 128 + h) * 2] = sr * (1.f / 128.f);
  Dt[(q * 128 + h) * 2 + 1] = si * (1.f / 128.f);
}

// ---------------- register FFT-2048: radix 8*8*8*4, 256 threads ----------------
// Natural-order output buffer index swizzle (breaks the 512-stride bank pattern)
#define SW(k) ((k) ^ (((k) >> 4) & 31))

template <int SGN>
__device__ __forceinline__ void dft8(cpx a[8]) {
  cpx t0 = cadd(a[0], a[4]), u0 = csub(a[0], a[4]);
  cpx t1 = cadd(a[1], a[5]), u1 = csub(a[1], a[5]);
  cpx t2 = cadd(a[2], a[6]), u2 = csub(a[2], a[6]);
  cpx t3 = cadd(a[3], a[7]), u3 = csub(a[3], a[7]);
  cpx E0 = cadd(t0, t2), E2 = csub(t0, t2);
  cpx ju2 = mulJ<SGN>(u2);
  cpx E1 = cadd(u0, ju2), E3 = csub(u0, ju2);
  cpx O0 = cadd(t1, t3), O2 = csub(t1, t3);
  cpx ju3 = mulJ<SGN>(u3);
  cpx O1 = cadd(u1, ju3), O3 = csub(u1, ju3);
  const float r = 0.70710678118654752f;
  const float S = (float)SGN;
  // w1 = e^{SGN*i*pi/4} = (r, S*r);  w3 = e^{SGN*3i*pi/4} = (-r, S*r)
  cpx w1O1 = make_float2(r * (O1.x - S * O1.y), r * (O1.y + S * O1.x));
  cpx w3O3 = make_float2(r * (-O3.x - S * O3.y), r * (S * O3.x - O3.y));
  cpx jO2 = mulJ<SGN>(O2);
  a[0] = cadd(E0, O0);   a[4] = csub(E0, O0);
  a[1] = cadd(E1, w1O1); a[5] = csub(E1, w1O1);
  a[2] = cadd(E2, jO2);  a[6] = csub(E2, jO2);
  a[3] = cadd(E3, w3O3); a[7] = csub(E3, w3O3);
}

template <int SGN>
__device__ __forceinline__ void dft4(cpx b[4]) {
  cpx s0 = cadd(b[0], b[2]), d0 = csub(b[0], b[2]);
  cpx s1 = cadd(b[1], b[3]), d1 = csub(b[1], b[3]);
  cpx jd1 = mulJ<SGN>(d1);
  b[0] = cadd(s0, s1); b[2] = csub(s0, s1);
  b[1] = cadd(d0, jd1); b[3] = csub(d0, jd1);
}

__device__ __forceinline__ void twid8(cpx a[8], float ang) {
  float s, c; sincosf(ang, &s, &c);
  cpx w1 = make_float2(c, s);
  cpx w2 = cmul(w1, w1), w3 = cmul(w2, w1), w4 = cmul(w2, w2);
  cpx w5 = cmul(w3, w2), w6 = cmul(w3, w3), w7 = cmul(w4, w3);
  a[1] = cmul(a[1], w1); a[2] = cmul(a[2], w2); a[3] = cmul(a[3], w3);
  a[4] = cmul(a[4], w4); a[5] = cmul(a[5], w5); a[6] = cmul(a[6], w6);
  a[7] = cmul(a[7], w7);
}

// On entry: a[j] = z[t + 256*j] (natural order input), t in [0,256).
// On exit: bufB[SW(k)] = X[k] = sum_n z[n] e^{SGN*2pi i nk/2048}.
template <int SGN>
__device__ __forceinline__ void fft2048_core(cpx a[8], cpx* __restrict__ bufA,
                                             cpx* __restrict__ bufB, int t) {
  const float S = (float)SGN;
  // stage 1: k = p + 8*k1; y_p[t] = DFT8_j(z[t+256j])[p] * W2048^{t p}
  dft8<SGN>(a);
  twid8(a, S * (2.f * PI_F / 2048.f) * (float)t);
#pragma unroll
  for (int p = 0; p < 8; ++p) bufA[p * 264 + t] = a[p];
  __syncthreads();
  // stage 2: FFT-256 radix-8: thread (p, n1)
  int p = t >> 5, n1 = t & 31;
#pragma unroll
  for (int j = 0; j < 8; ++j) a[j] = bufA[p * 264 + n1 + 32 * j];
  dft8<SGN>(a);
  twid8(a, S * (2.f * PI_F / 256.f) * (float)n1);
#pragma unroll
  for (int q = 0; q < 8; ++q) bufB[p * 264 + q * 33 + n1] = a[q];
  __syncthreads();
  // stage 3: FFT-32 radix-8: thread (p, q, n2)
  int q = (t >> 2) & 7, n2 = t & 3;
#pragma unroll
  for (int j = 0; j < 8; ++j) a[j] = bufB[p * 264 + q * 33 + n2 + 4 * j];
  dft8<SGN>(a);
  twid8(a, S * (2.f * PI_F / 32.f) * (float)n2);
#pragma unroll
  for (int d = 0; d < 8; ++d) bufA[p * 264 + q * 33 + 4 * d + n2] = a[d];
  __syncthreads();
  // stage 4: FFT-4, thread handles d = 2*n2, 2*n2+1; X[p+8q+64d+512c]
#pragma unroll
  for (int h = 0; h < 2; ++h) {
    int d = 2 * n2 + h;
    cpx b[4];
#pragma unroll
    for (int m = 0; m < 4; ++m) b[m] = bufA[p * 264 + q * 33 + 4 * d + m];
    dft4<SGN>(b);
    int kb = p + 8 * q + 64 * d;
#pragma unroll
    for (int c = 0; c < 4; ++c) bufB[SW(kb + 512 * c)] = b[c];
  }
  __syncthreads();
}

// ---------------- forward rfft-4096 per (b,h) row ----------------
__global__ __launch_bounds__(256, 4) void fft_fwd(const float* __restrict__ u,
                                                  cpx* __restrict__ U) {
  __shared__ cpx bufA[2112], bufB[2112];
  int t = threadIdx.x;
  int row = blockIdx.x;
  const cpx* src = (const cpx*)(u + (size_t)row * NL);
  cpx a[8];
#pragma unroll
  for (int j = 0; j < 8; ++j) a[j] = src[t + 256 * j];
  fft2048_core<-1>(a, bufA, bufB, t);
  cpx* Urow = U + (size_t)row * LF;
#pragma unroll
  for (int r = 0; r < 4; ++r) {
    int k = t + (r << 8);
    if (k == 0) {
      cpx z0 = bufB[SW(0)];
      Urow[0] = make_float2(z0.x + z0.y, 0.f);
      Urow[2048] = make_float2(z0.x - z0.y, 0.f);
      cpx zN = bufB[SW(1024)];
      Urow[1024] = make_float2(zN.x, -zN.y);
    } else {
      cpx A = bufB[SW(k)];
      cpx M = bufB[SW(2048 - k)];
      float Br = M.x, Bi = -M.y;
      float sr = 0.5f * (A.x + Br), si = 0.5f * (A.y + Bi);
      float dr = 0.5f * (A.x - Br), di = 0.5f * (A.y - Bi);
      float th = (float)k * (PI_F / 2048.f);
      float sn, cs; sincosf(th, &sn, &cs);
      float tr = cs * dr + sn * di;
      float ti = cs * di - sn * dr;
      Urow[k] = make_float2(sr + ti, si - tr);
      float A2r = M.x, A2i = M.y;
      float B2r = A.x, B2i = -A.y;
      float s2r = 0.5f * (A2r + B2r), s2i = 0.5f * (A2i + B2i);
      float d2r = 0.5f * (A2r - B2r), d2i = 0.5f * (A2i - B2i);
      float t2r = -cs * d2r + sn * d2i;
      float t2i = -cs * d2i - sn * d2r;
      Urow[2048 - k] = make_float2(s2r + t2i, s2i - t2r);
    }
  }
}

// ---------------- mixing: Y = C~ diag(kernel) B~ U + D~ U ----------------
__device__ __forceinline__ void ld8(float4 d[8], const float4* __restrict__ p) {
#pragma unroll
  for (int kk = 0; kk < 8; ++kk) d[kk] = p[kk];
}
__device__ __forceinline__ void cmac8(const float4 m[8], float xr, float xi,
                                      float ar[16], float ai[16]) {
#pragma unroll
  for (int kk = 0; kk < 8; ++kk) {
    float4 v = m[kk];
    ar[2 * kk]     = fmaf(v.x, xr, fmaf(-v.y, xi, ar[2 * kk]));
    ai[2 * kk]     = fmaf(v.x, xi, fmaf( v.y, xr, ai[2 * kk]));
    ar[2 * kk + 1] = fmaf(v.z, xr, fmaf(-v.w, xi, ar[2 * kk + 1]));
    ai[2 * kk + 1] = fmaf(v.z, xi, fmaf( v.w, xr, ai[2 * kk + 1]));
  }
}

__global__ __launch_bounds__(256, 2) void mix_kernel(
    const cpx* __restrict__ U,
    const float* __restrict__ Bt, const float* __restrict__ Ct,
    const float* __restrict__ Dt, const float* __restrict__ Lam,
    cpx* __restrict__ Y) {
  __shared__ float sUr[128][32], sUi[128][32], sVr[128][32], sVi[128][32];
  int tid = threadIdx.x;
  int b = blockIdx.y;
  size_t ub = (size_t)b * NH * LF;

  if (blockIdx.x == 64) {  // Nyquist column l = 2048
    int t = tid;
    if (t < 128) {
      cpx v = U[ub + (size_t)t * LF + 2048];
      sUr[t][0] = v.x; sUi[t][0] = v.y;
    }
    __syncthreads();
    if (t < 128) {
      float ar = 0.f, ai = 0.f;
      for (int q = 0; q < 128; ++q) {
        float ur = sUr[q][0], ui = sUi[q][0];
        float br = Bt[(q * 128 + t) * 2], bi = Bt[(q * 128 + t) * 2 + 1];
        ar = fmaf(br, ur, fmaf(-bi, ui, ar));
        ai = fmaf(br, ui, fmaf(bi, ur, ai));
      }
      float a = Lam[2 * t], bb = Lam[2 * t + 1];
      float dx = -a, dy = PI_F - bb;
      float inv = 1.f / (dx * dx + dy * dy);
      float kr = dx * inv, ki = -dy * inv;
      sVr[t][0] = kr * ar - ki * ai;
      sVi[t][0] = kr * ai + ki * ar;
    }
    __syncthreads();
    if (t < 128) {
      float ar = 0.f, ai = 0.f;
      for (int q = 0; q < 128; ++q) {
        float ur = sUr[q][0], ui = sUi[q][0];
        float vr = sVr[q][0], vi = sVi[q][0];
        float cr = Ct[(q * 128 + t) * 2], ci = Ct[(q * 128 + t) * 2 + 1];
        float dr = Dt[(q * 128 + t) * 2], di = Dt[(q * 128 + t) * 2 + 1];
        ar += cr * vr - ci * vi + dr * ur - di * ui;
        ai += cr * vi + ci * vr + dr * ui + di * ur;
      }
      Y[ub + (size_t)t * LF + 2048] = make_float2(ar, ai);
    }
    return;
  }

  int lane = tid & 31, g = tid >> 5;   // 8 groups of 32 lanes
  int l = blockIdx.x * 32 + lane;      // l <= 2047 always valid
#pragma unroll
  for (int rep = 0; rep < 16; ++rep) {
    int q = rep * 8 + g;
    cpx v = U[ub + (size_t)q * LF + l];
    sUr[q][lane] = v.x; sUi[q][lane] = v.y;
  }
  __syncthreads();
  float omega = (float)l * (PI_F / 2048.f);

  float ar[16], ai[16];
  // ---- pass 1: V = B~ U (panel p0..p0+15), software-pipelined loads ----
  {
#pragma unroll
    for (int k = 0; k < 16; ++k) { ar[k] = 0.f; ai[k] = 0.f; }
    const float4* base = (const float4*)Bt + g * 8;  // + q*64 per row
    float4 e[8], o[8];
    ld8(e, base);
#pragma unroll 1
    for (int q = 0; q < 128; q += 2) {
      ld8(o, base + (q + 1) * 64);
      cmac8(e, sUr[q][lane], sUi[q][lane], ar, ai);
      ld8(e, base + ((q + 2) & 127) * 64);
      cmac8(o, sUr[q + 1][lane], sUi[q + 1][lane], ar, ai);
    }
    int p0 = g * 16;
#pragma unroll
    for (int k = 0; k < 16; ++k) {
      int p = p0 + k;
      float a = Lam[2 * p], bb = Lam[2 * p + 1];
      float dx = -a, dy = omega - bb;
      float inv = 1.f / (dx * dx + dy * dy);
      float kr = dx * inv, ki = -dy * inv;  // 1/(i*omega - lambda)
      sVr[p][lane] = kr * ar[k] - ki * ai[k];
      sVi[p][lane] = kr * ai[k] + ki * ar[k];
    }
  }
  __syncthreads();

  // ---- pass 2a: Y += C~ V ----
  {
#pragma unroll
    for (int k = 0; k < 16; ++k) { ar[k] = 0.f; ai[k] = 0.f; }
    const float4* base = (const float4*)Ct + g * 8;
    float4 e[8], o[8];
    ld8(e, base);
#pragma unroll 1
    for (int q = 0; q < 128; q += 2) {
      ld8(o, base + (q + 1) * 64);
      cmac8(e, sVr[q][lane], sVi[q][lane], ar, ai);
      ld8(e, base + ((q + 2) & 127) * 64);
      cmac8(o, sVr[q + 1][lane], sVi[q + 1][lane], ar, ai);
    }
  }
  // ---- pass 2b: Y += D~ U ----
  {
    const float4* base = (const float4*)Dt + g * 8;
    float4 e[8], o[8];
    ld8(e, base);
#pragma unroll 1
    for (int q = 0; q < 128; q += 2) {
      ld8(o, base + (q + 1) * 64);
      cmac8(e, sUr[q][lane], sUi[q][lane], ar, ai);
      ld8(e, base + ((q + 2) & 127) * 64);
      cmac8(o, sUr[q + 1][lane], sUi[q + 1][lane], ar, ai);
    }
  }
  int h0 = g * 16;
#pragma unroll
  for (int k = 0; k < 16; ++k) {
    Y[ub + (size_t)(h0 + k) * LF + l] = make_float2(ar[k], ai[k]);
  }
}

// ---------------- inverse rfft-4096 per (b,h) row, fused exact GELU ----------------
__global__ __launch_bounds__(256, 4) void fft_inv_gelu(const cpx* __restrict__ Y,
                                                       float* __restrict__ out) {
  __shared__ cpx bufA[2112], bufB[2112];
  int t = threadIdx.x;
  int row = blockIdx.x;
  const cpx* Yrow = Y + (size_t)row * LF;
#pragma unroll
  for (int r = 0; r < 4; ++r) {
    int k = t + (r << 8);
    if (k == 0) {
      float y0 = Yrow[0].x;     // Im discarded (pocketfft irfft semantics)
      float yN = Yrow[2048].x;
      bufB[SW(0)] = make_float2(0.5f * (y0 + yN), 0.5f * (y0 - yN));
      cpx z = Yrow[1024];
      bufB[SW(1024)] = make_float2(z.x, -z.y);
    } else {
      cpx A = Yrow[k];
      cpx M = Yrow[2048 - k];
      float Br = M.x, Bi = -M.y;
      float sr = 0.5f * (A.x + Br), si = 0.5f * (A.y + Bi);
      float dr = 0.5f * (A.x - Br), di = 0.5f * (A.y - Bi);
      float th = (float)k * (PI_F / 2048.f);
      float sn, cs; sincosf(th, &sn, &cs);
      float e1 = cs * di + sn * dr;
      float e2 = cs * dr - sn * di;
      bufB[SW(k)] = make_float2(sr - e1, si + e2);
      bufB[SW(2048 - k)] = make_float2(sr + e1, -si + e2);
    }
  }
  __syncthreads();
  cpx a[8];
#pragma unroll
  for (int j = 0; j < 8; ++j) a[j] = bufB[SW(t + 256 * j)];
  fft2048_core<1>(a, bufA, bufB, t);
  float2* dst = (float2*)(out + (size_t)row * NL);
  const float sc = 1.f / 2048.f;
#pragma unroll
  for (int r = 0; r < 8; ++r) {
    int n = t + (r << 8);
    cpx z = bufB[SW(n)];
    dst[n] = make_float2(gelu_exact(z.x * sc), gelu_exact(z.y * sc));
  }
}

extern "C" void kernel_launch(void* const* d_in, const int* in_sizes, int n_in,
                              void* d_out, int out_size, void* d_ws, size_t ws_size,
                              hipStream_t stream) {
  const float* u   = (const float*)d_in[0];
  const float* C2  = (const float*)d_in[1];
  const float* B2  = (const float*)d_in[2];
  const float* D   = (const float*)d_in[3];
  const float* Lam = (const float*)d_in[4];
  float* out = (float*)d_out;
  float* ws = (float*)d_ws;

  const size_t nUc = (size_t)NB * NH * LF;   // complex elements per plane
  cpx *U, *Yp;
  float* Bt;
  size_t need_full = (4 * nUc + 4 * 32768) * sizeof(float);
  if (ws_size >= need_full) {
    U = (cpx*)ws;
    Yp = U + nUc;
    Bt = ws + 4 * nUc;
  } else {
    // Alias Y onto U: each (b,l) column is fully read into LDS by its owning
    // mix block before that block writes Y to the same column.
    U = (cpx*)ws;
    Yp = U;
    Bt = ws + 2 * nUc;
  }
  float* Ct = Bt + 32768;
  float* Dt = Ct + 32768;
  float* Tt = Dt + 32768;

  precomp1<<<dim3(128, 3), 128, 0, stream>>>(C2, B2, D, Bt, Ct, Tt);
  precomp2<<<128, 128, 0, stream>>>(Tt, Dt);
  fft_fwd<<<NB * NH, 256, 0, stream>>>(u, U);
  mix_kernel<<<dim3(65, NB), 256, 0, stream>>>(U, Bt, Ct, Dt, Lam, Yp);
  fft_inv_gelu<<<NB * NH, 256, 0, stream>>>(Yp, out);
}